// Round 9
// baseline (259.915 us; speedup 1.0000x reference)
//
#include <hip/hip_runtime.h>
#include <math.h>

#define L2E 1.44269504088896340736f   // log2(e)
#define LN2 0.69314718055994530942f   // ln(2)
#define ITERS 4                       // 64-row chunks per wave
// block = 4 waves; rows/block = 4 waves * ITERS * 64 = 1024

#if __has_builtin(__builtin_amdgcn_exp2f)
__device__ __forceinline__ float fexp2(float x)  { return __builtin_amdgcn_exp2f(x); }
#else
__device__ __forceinline__ float fexp2(float x)  { return __exp2f(x); }
#endif
#if __has_builtin(__builtin_amdgcn_logf)
__device__ __forceinline__ float flog2(float x)  { return __builtin_amdgcn_logf(x); }
#else
__device__ __forceinline__ float flog2(float x)  { return __log2f(x); }
#endif

// s_waitcnt imm: vmcnt[3:0] | expcnt<<4 | lgkmcnt<<8 | vmcnt[5:4]<<14
// vmcnt(4), expcnt/lgkmcnt = no-wait: 4 | 0x70 | 0xF00 = 0xF74
#define WAITCNT_VM4 0xF74

// Full row contribution (tail path only — empty at B=2^21).
__device__ __forceinline__ float row_contrib_full(
    const float* __restrict__ pb, const float4* __restrict__ pt4,
    const float4* __restrict__ ps4, const float* __restrict__ tb,
    const float4* __restrict__ tt4, const int* __restrict__ ts,
    const float* __restrict__ psf, int row)
{
    float  xb = pb[row], yb = tb[row];
    int    lab = ts[row];
    float4 xt = pt4[row], yt = tt4[row];
    size_t b = (size_t)row * 4;
    float4 r0 = ps4[b+0], r1 = ps4[b+1], r2 = ps4[b+2], r3 = ps4[b+3];
    float vlab = psf[(size_t)row * 16 + lab];
    float v[16] = { r0.x,r0.y,r0.z,r0.w, r1.x,r1.y,r1.z,r1.w,
                    r2.x,r2.y,r2.z,r2.w, r3.x,r3.y,r3.z,r3.w };
    float s = 0.0f;
    for (int j = 0; j < 16; ++j) s += fexp2(v[j] * L2E);
    float g = fexp2(xb * L2E);
    float p = (1.0f+fexp2(xt.x*L2E))*(1.0f+fexp2(xt.y*L2E))
            * (1.0f+fexp2(xt.z*L2E))*(1.0f+fexp2(xt.w*L2E));
    float c = LN2 * (flog2(s * (1.0f+g)) + 0.25f * flog2(p));
    float dot = xt.x*yt.x + xt.y*yt.y + xt.z*yt.z + xt.w*yt.w;
    c = c - vlab - yb*xb - 0.25f*dot;
    bool bin_c  = (xb >= 0.0f);
    bool type_c = fmaxf(fmaxf(xt.x,xt.y), fmaxf(xt.z,xt.w)) >= 0.0f;
    float mr = v[1];
    for (int j = 2; j < 16; ++j) mr = fmaxf(mr, v[j]);
    bool src_c = (mr > v[0]);
    c += (bin_c != type_c) ? 1.0f : 0.0f;
    c += (bin_c != src_c)  ? 1.0f : 0.0f;
    return c;
}

// Wave-private LDS double-buffered pipeline for the ps stream.
// DMA has no register result -> compiler cannot sink it -> 4 kB/wave
// guaranteed in flight across the compute phase. No barriers in hot loop.
__global__ __launch_bounds__(256) void multitask_loss_kernel(
    const float*  __restrict__ pb,
    const float4* __restrict__ pt4,
    const float*  __restrict__ ps,    // scalar view
    const float*  __restrict__ tb,
    const float4* __restrict__ tt4,
    const int*    __restrict__ ts,
    float*        __restrict__ partials)
{
    __shared__ float lps[4][2][1024];   // [wave][buf][64 rows x 16]

    const int tid  = threadIdx.x;
    const int lane = tid & 63;
    const int wave = tid >> 6;
    const size_t wbase = (size_t)blockIdx.x * 1024 + (size_t)wave * (64 * ITERS);

    // ---- prologue: DMA chunk 0 into buf 0 ----
    {
        const float* g = ps + wbase * 16;
        #pragma unroll
        for (int j = 0; j < 4; ++j)
            __builtin_amdgcn_global_load_lds(
                (const __attribute__((address_space(1))) void*)(g + j*256 + lane*4),
                (__attribute__((address_space(3))) void*)(&lps[wave][0][j*256]),
                16, 0, 0);
    }

    const int rot0 = (lane + ((lane >> 4) & 1)) & 15;   // 2-way-only bank schedule
    float acc = 0.0f;

    #pragma unroll
    for (int c = 0; c < ITERS; ++c) {
        const int row = (int)(wbase + c * 64) + lane;

        // 1) direct small-stream loads for chunk c (oldest in vmcnt queue)
        float  xb = pb[row];
        float  yb = tb[row];
        int    lab = ts[row];
        float4 xt = pt4[row];
        float4 yt = tt4[row];
        __builtin_amdgcn_sched_barrier(0);   // keep directs before the DMA

        // 2) DMA chunk c+1 into the alternate buffer (4 newest vmcnt ops)
        if (c + 1 < ITERS) {
            const float* g = ps + (wbase + (size_t)(c + 1) * 64) * 16;
            float* l = &lps[wave][(c + 1) & 1][0];
            #pragma unroll
            for (int j = 0; j < 4; ++j)
                __builtin_amdgcn_global_load_lds(
                    (const __attribute__((address_space(1))) void*)(g + j*256 + lane*4),
                    (__attribute__((address_space(3))) void*)(l + j*256),
                    16, 0, 0);
        }
        __builtin_amdgcn_sched_barrier(0);

        // 3) drain chunk c's DMA + directs; leave chunk c+1's DMA in flight
        __builtin_amdgcn_s_waitcnt(WAITCNT_VM4);
        __builtin_amdgcn_sched_barrier(0);   // ds_reads must not hoist above

        // 4) compute chunk c
        const float* lv = &lps[wave][c & 1][lane * 16];

        float s0 = 0.0f, s1 = 0.0f;
        float m0 = -INFINITY, m1 = -INFINITY;
        float v0 = 0.0f;
        #pragma unroll
        for (int d = 0; d < 16; ++d) {
            int   cls = (d + rot0) & 15;
            float val = lv[cls];                 // bank 2-way only (free)
            if (d & 1) { s1 += fexp2(val * L2E); m1 = fmaxf(m1, val); }
            else       { s0 += fexp2(val * L2E); m0 = fmaxf(m0, val); }
            v0 = (cls == 0) ? val : v0;
        }
        float S    = s0 + s1;
        float mall = fmaxf(m0, m1);
        float vlab = lv[lab];                    // ~2-way avg gather in LDS

        float g  = fexp2(xb * L2E);
        float f0 = fexp2(xt.x*L2E), f1 = fexp2(xt.y*L2E);
        float f2 = fexp2(xt.z*L2E), f3 = fexp2(xt.w*L2E);
        float p  = ((1.0f+f0)*(1.0f+f1)) * ((1.0f+f2)*(1.0f+f3));

        float dot = xt.x*yt.x + xt.y*yt.y + xt.z*yt.z + xt.w*yt.w;
        float cc = LN2 * (flog2(S * (1.0f + g)) + 0.25f * flog2(p))
                 - vlab - yb*xb - 0.25f*dot;

        bool bin_c  = (xb >= 0.0f);
        bool type_c = fmaxf(fmaxf(xt.x, xt.y), fmaxf(xt.z, xt.w)) >= 0.0f;
        bool src_c  = (mall > v0);               // argmax > 0 (first-max ties)

        unsigned long long mb = __ballot(bin_c);
        unsigned long long mt = __ballot(type_c);
        unsigned long long ms = __ballot(src_c);
        int pen = __popcll(mb ^ mt) + __popcll(mb ^ ms);   // wave-uniform

        acc += cc + (float)pen * (1.0f / 64.0f);  // spread pen across lanes? no-
        // (pen is wave-uniform; adding it on every lane would count it 64x.
        //  Divide by 64 so the wave-sum adds it exactly once.)
    }

    // ---- wave reduce + block partial ----
    #pragma unroll
    for (int off = 32; off > 0; off >>= 1)
        acc += __shfl_down(acc, off, 64);

    __shared__ float wsum[4];
    if (lane == 0) wsum[wave] = acc;
    __syncthreads();
    if (tid == 0)
        partials[blockIdx.x] = wsum[0] + wsum[1] + wsum[2] + wsum[3];
}

__global__ __launch_bounds__(256) void reduce_kernel(
    const float* __restrict__ partials, int nblocks,
    const float*  __restrict__ pb,  const float4* __restrict__ pt4,
    const float4* __restrict__ ps4, const float*  __restrict__ tb,
    const float4* __restrict__ tt4, const int*    __restrict__ ts,
    const float*  __restrict__ psf,
    int n_main, int B, float* __restrict__ out, double invB)
{
    double s = 0.0;
    for (int i = threadIdx.x; i < nblocks; i += 256)
        s += (double)partials[i];
    for (int r = n_main + threadIdx.x; r < B; r += 256)
        s += (double)row_contrib_full(pb, pt4, ps4, tb, tt4, ts, psf, r);

    #pragma unroll
    for (int off = 32; off > 0; off >>= 1)
        s += __shfl_down(s, off, 64);

    __shared__ double wsum[4];
    int lane = threadIdx.x & 63;
    int wave = threadIdx.x >> 6;
    if (lane == 0) wsum[wave] = s;
    __syncthreads();
    if (threadIdx.x == 0)
        out[0] = (float)((wsum[0] + wsum[1] + wsum[2] + wsum[3]) * invB);
}

extern "C" void kernel_launch(void* const* d_in, const int* in_sizes, int n_in,
                              void* d_out, int out_size, void* d_ws, size_t ws_size,
                              hipStream_t stream) {
    const float*  pb  = (const float*)d_in[0];
    const float4* pt4 = (const float4*)d_in[1];
    const float*  psf = (const float*)d_in[2];
    const float4* ps4 = (const float4*)d_in[2];
    const float*  tb  = (const float*)d_in[3];
    const float4* tt4 = (const float4*)d_in[4];
    const int*    ts  = (const int*)d_in[5];
    int B = in_sizes[0];                       // 2097152 = 2048 * 1024

    float* partials = (float*)d_ws;            // [blocks] fully overwritten

    int blocks = B / 1024;                     // 2048
    int n_main = blocks * 1024;                // tail (empty here) in reduce

    multitask_loss_kernel<<<blocks, 256, 0, stream>>>(pb, pt4, psf, tb, tt4, ts,
                                                      partials);
    reduce_kernel<<<1, 256, 0, stream>>>(partials, blocks,
                                         pb, pt4, ps4, tb, tt4, ts, psf,
                                         n_main, B, (float*)d_out,
                                         1.0 / (double)B);
}